// Round 11
// baseline (698.052 us; speedup 1.0000x reference)
//
#include <hip/hip_runtime.h>
#include <hip/hip_bf16.h>
#include <math.h>

#define N_NODES 100000
#define N_EDGES 3200000
#define NUM_GRAPHS 2048
#define IN_CH 35
#define HID 128
#define BN_EPS 1e-5f

#define BUCK_SHIFT 9
#define BUCK_SIZE 512
#define NB_BUCK 196          // ceil(100000/512)
#define BUCK_CAP 18432       // epack capacity/bucket (mean 16327 + ~16 sigma)
#define COL_CAP 19456        // col capacity/bucket (holds padded rows + slack)
#define BIN_GRID 1024
#define BIN_CHUNK 3128       // multiple of 4; 1024*3128 >= 3.2M

typedef short bf16x8 __attribute__((ext_vector_type(8)));
typedef float f32x4 __attribute__((ext_vector_type(4)));

__device__ __forceinline__ float gelu_f(float x) {
    return 0.5f * x * (1.0f + erff(x * 0.70710678118654752440f));
}

__device__ __forceinline__ float bflo(unsigned v) { return __uint_as_float(v << 16); }
__device__ __forceinline__ float bfhi(unsigned v) { return __uint_as_float(v & 0xffff0000u); }
__device__ __forceinline__ unsigned f2bf(float f) {
    unsigned x = __float_as_uint(f);
    return (x + 0x7fffu + ((x >> 16) & 1u)) >> 16;   // RNE
}
__device__ __forceinline__ unsigned packbf2(float lo, float hi) {
    return f2bf(lo) | (f2bf(hi) << 16);
}

// ---------------- init: W2/W3 transpose-cast + zero counters/stats/pad rows ----------------

__global__ void k_init(int* __restrict__ gcnt, float* __restrict__ stats,
                       unsigned* __restrict__ xzero, unsigned* __restrict__ hzero,
                       const float* __restrict__ W2, const float* __restrict__ W3,
                       unsigned* __restrict__ Wt2, unsigned* __restrict__ Wt3) {
    if (blockIdx.x < 64) {
        int t = blockIdx.x * 256 + threadIdx.x;   // 0..16383
        const float* W = (t < 8192) ? W2 : W3;
        unsigned* Wt = (t < 8192) ? Wt2 : Wt3;
        int i = t & 8191;
        int n = i >> 6, j = i & 63;
        Wt[n * 64 + j] = packbf2(W[(2 * j) * HID + n], W[(2 * j + 1) * HID + n]);
    } else {
        int i = threadIdx.x;
        if (i < NB_BUCK) gcnt[i] = 0;
        for (int k = i; k < 3 * 256; k += 256) stats[k] = 0.0f;
        if (i < 32) xzero[i] = 0u;
        if (i < 64) hzero[i] = 0u;
    }
}

// ---------------- bin: one pass, fixed-capacity buckets, packed edges ----------------
// edge word: src (bits 0..16) | (dst & 511) (bits 17..25)

__global__ void k_bin(const int* __restrict__ ei, int* __restrict__ gcnt,
                      unsigned* __restrict__ epack) {
    __shared__ unsigned lpack[BIN_CHUNK];
    __shared__ unsigned char lbuck[BIN_CHUNK];
    __shared__ int hist[NB_BUCK];
    __shared__ int hbase[NB_BUCK];
    __shared__ int lcur[NB_BUCK];
    int tid = threadIdx.x;
    if (tid < NB_BUCK) { hist[tid] = 0; lcur[tid] = 0; }
    __syncthreads();
    int e0 = blockIdx.x * BIN_CHUNK;
    int nE = min(e0 + BIN_CHUNK, N_EDGES) - e0;   // multiple of 4
    for (int i = tid * 4; i < nE; i += 1024) {
        int4 s4 = *(const int4*)(ei + e0 + i);
        int4 d4 = *(const int4*)(ei + N_EDGES + e0 + i);
        lpack[i + 0] = (unsigned)s4.x | (((unsigned)d4.x & 511u) << 17);
        lpack[i + 1] = (unsigned)s4.y | (((unsigned)d4.y & 511u) << 17);
        lpack[i + 2] = (unsigned)s4.z | (((unsigned)d4.z & 511u) << 17);
        lpack[i + 3] = (unsigned)s4.w | (((unsigned)d4.w & 511u) << 17);
        int b0 = d4.x >> BUCK_SHIFT, b1 = d4.y >> BUCK_SHIFT;
        int b2 = d4.z >> BUCK_SHIFT, b3 = d4.w >> BUCK_SHIFT;
        lbuck[i + 0] = (unsigned char)b0;
        lbuck[i + 1] = (unsigned char)b1;
        lbuck[i + 2] = (unsigned char)b2;
        lbuck[i + 3] = (unsigned char)b3;
        atomicAdd(&hist[b0], 1);
        atomicAdd(&hist[b1], 1);
        atomicAdd(&hist[b2], 1);
        atomicAdd(&hist[b3], 1);
    }
    __syncthreads();
    if (tid < NB_BUCK) {
        int h = hist[tid];
        hbase[tid] = (h > 0) ? (tid * BUCK_CAP + atomicAdd(&gcnt[tid], h)) : 0;
    }
    __syncthreads();
    for (int i = tid; i < nE; i += 256) {
        int b = lbuck[i];
        int off = atomicAdd(&lcur[b], 1);
        epack[hbase[b] + off] = lpack[i];
    }
}

// ---------------- fill: degree, rowp (4-padded), dinv, CSR col, fused X cast ----------------

__global__ __launch_bounds__(512) void k_fill(
        const int* __restrict__ gcnt, const unsigned* __restrict__ epack,
        int* __restrict__ rowp, int* __restrict__ rowpEnd,
        float* __restrict__ dinv, int* __restrict__ col,
        const float* __restrict__ X, unsigned* __restrict__ Xb) {
    __shared__ int ldeg[BUCK_SIZE];
    __shared__ int sa[BUCK_SIZE];
    __shared__ int sb[BUCK_SIZE];
    __shared__ int lcur[BUCK_SIZE];
    __shared__ float dl[BUCK_SIZE];
    int b = blockIdx.x;
    int tid = threadIdx.x;
    int base_node = b << BUCK_SHIFT;
    int nn = min(BUCK_SIZE, N_NODES - base_node);
    int seg0e = b * BUCK_CAP;
    int seg1e = seg0e + gcnt[b];
    int seg0c = b * COL_CAP;
    ldeg[tid] = 0;
    __syncthreads();
    for (int e = seg0e + tid; e < seg1e; e += BUCK_SIZE)
        atomicAdd(&ldeg[epack[e] >> 17], 1);
    __syncthreads();
    int deg = ldeg[tid];
    int pdeg = (deg + 3) & ~3;         // pad each row to multiple of 4
    sa[tid] = pdeg;
    __syncthreads();
    int* src = sa; int* dst = sb;
    for (int st = 1; st < BUCK_SIZE; st <<= 1) {
        int v = src[tid];
        if (tid >= st) v += src[tid - st];
        dst[tid] = v;
        __syncthreads();
        int* t = src; src = dst; dst = t;
    }
    int ex = (tid == 0) ? 0 : src[tid - 1];
    int total = src[BUCK_SIZE - 1];
    int rp = seg0c + ex;
    lcur[tid] = rp;
    float dv = rsqrtf((float)(deg + 1));
    dl[tid] = dv;
    if (tid < nn) {
        rowp[base_node + tid] = rp;
        rowpEnd[base_node + tid] = rp + pdeg;
        dinv[base_node + tid] = dv;
    }
    __syncthreads();
    // place edges (into [rp, rp+deg) slots)
    for (int e = seg0e + tid; e < seg1e; e += BUCK_SIZE) {
        unsigned v = epack[e];
        int p = atomicAdd(&lcur[v >> 17], 1);
        col[p] = (int)(v & 0x1FFFFu);
    }
    // row pad fill (disjoint from placement range)
    if (tid < nn) {
        for (int p = rp + deg; p < rp + pdeg; ++p) col[p] = N_NODES;
    }
    // bucket tail fill so conv overshoot reads the zero row
    for (int p = seg0c + total + tid; p < seg0c + COL_CAP; p += BUCK_SIZE)
        col[p] = N_NODES;
    // fused X cast: Xb[n] = dinv[n] * X[n] (bf16, 128B rows)
    for (int idx = tid; idx < nn * 32; idx += BUCK_SIZE) {
        int nl = idx >> 5, j = idx & 31;
        int n = base_node + nl;
        float dvn = dl[nl];
        float lo = 0.0f, hi = 0.0f;
        if (j < 17) {
            lo = X[(size_t)n * IN_CH + 2 * j];
            hi = X[(size_t)n * IN_CH + 2 * j + 1];
        } else if (j == 17) {
            lo = X[(size_t)n * IN_CH + 34];
        }
        Xb[(size_t)n * 32 + j] = packbf2(dvn * lo, dvn * hi);
    }
}

#define ACC8(v) { a0 += bflo(v.x); a1 += bfhi(v.x); a2 += bflo(v.y); a3 += bfhi(v.y); \
                  a4 += bflo(v.z); a5 += bfhi(v.z); a6 += bflo(v.w); a7 += bfhi(v.w); }

// ---------------- fused layer-1: Y1 = (A_norm X) W1 + b1 -> bf16 ----------------
// 8 waves = 8 nodes/block. Wave = 8 groups x 8 lanes; group g owns 4-edge runs
// (one int4 idx load, prefetched); lane j loads uint4 -> 8 lanes cover 128B row.
// Rows 4-padded -> per-group predication only. 32 edges per iteration.

#define C1_NODES 8

__global__ __launch_bounds__(512) void k_conv1(
        const unsigned* __restrict__ Xb, const int* __restrict__ rowp,
        const int* __restrict__ rowpEnd, const int* __restrict__ col,
        const float* __restrict__ dinv,
        const float* __restrict__ W1, const float* __restrict__ b1,
        unsigned* __restrict__ Yb) {
    __shared__ float w_s[IN_CH * HID];       // 17.9 KB
    __shared__ float b_s[HID];
    __shared__ float xa_s[C1_NODES][40];
    int tid = threadIdx.x;
    for (int u = tid; u < IN_CH * HID; u += 512) w_s[u] = W1[u];
    if (tid < HID) b_s[tid] = b1[tid];

    int wid = tid >> 6;
    int lane = tid & 63;
    int g = lane >> 3;           // 8 groups
    int j = lane & 7;            // uint4 slot within 128B row
    int node = blockIdx.x * C1_NODES + wid;
    bool valid = node < N_NODES;

    float a0 = 0, a1 = 0, a2 = 0, a3 = 0, a4 = 0, a5 = 0, a6 = 0, a7 = 0;
    float di = 0.0f;
    if (valid) {
        int rp0 = rowp[node], rp1 = rowpEnd[node];
        di = dinv[node];
        uint4 sv = *(const uint4*)(Xb + (size_t)node * 32 + j * 4);
        float w0 = (g == 0) ? 1.0f : 0.0f;
        a0 = w0 * bflo(sv.x); a1 = w0 * bfhi(sv.x);
        a2 = w0 * bflo(sv.y); a3 = w0 * bfhi(sv.y);
        a4 = w0 * bflo(sv.z); a5 = w0 * bfhi(sv.z);
        a6 = w0 * bflo(sv.w); a7 = w0 * bfhi(sv.w);
        if (rp0 < rp1) {
            int4 cs = *(const int4*)(col + rp0 + 4 * g);
            for (int e0 = rp0; e0 < rp1; e0 += 32) {
                int4 nx = *(const int4*)(col + e0 + 32 + 4 * g);   // prefetch
                bool v = (e0 + 4 * g) < rp1;
                int s0 = v ? cs.x : N_NODES;
                int s1 = v ? cs.y : N_NODES;
                int s2 = v ? cs.z : N_NODES;
                int s3 = v ? cs.w : N_NODES;
                uint4 v0 = *(const uint4*)(Xb + (size_t)s0 * 32 + j * 4);
                uint4 v1 = *(const uint4*)(Xb + (size_t)s1 * 32 + j * 4);
                uint4 v2 = *(const uint4*)(Xb + (size_t)s2 * 32 + j * 4);
                uint4 v3 = *(const uint4*)(Xb + (size_t)s3 * 32 + j * 4);
                ACC8(v0); ACC8(v1); ACC8(v2); ACC8(v3);
                cs = nx;
            }
        }
    }
    // reduce 8 groups -> group 0 (3 shuffle stages)
    #define RED(o) { a0 += __shfl(a0,(lane+o)&63,64); a1 += __shfl(a1,(lane+o)&63,64); \
                     a2 += __shfl(a2,(lane+o)&63,64); a3 += __shfl(a3,(lane+o)&63,64); \
                     a4 += __shfl(a4,(lane+o)&63,64); a5 += __shfl(a5,(lane+o)&63,64); \
                     a6 += __shfl(a6,(lane+o)&63,64); a7 += __shfl(a7,(lane+o)&63,64); }
    RED(32); RED(16); RED(8);
    #undef RED
    if (valid && g == 0 && j < 5) {
        xa_s[wid][8 * j + 0] = di * a0;
        xa_s[wid][8 * j + 1] = di * a1;
        xa_s[wid][8 * j + 2] = di * a2;
        xa_s[wid][8 * j + 3] = di * a3;
        xa_s[wid][8 * j + 4] = di * a4;
        xa_s[wid][8 * j + 5] = di * a5;
        xa_s[wid][8 * j + 6] = di * a6;
        xa_s[wid][8 * j + 7] = di * a7;
    }
    __syncthreads();
    float acc0 = b_s[2 * lane];
    float acc1 = b_s[2 * lane + 1];
    #pragma unroll 7
    for (int k = 0; k < IN_CH; ++k) {
        float xv = xa_s[wid][k];
        acc0 = fmaf(xv, w_s[k * HID + 2 * lane], acc0);
        acc1 = fmaf(xv, w_s[k * HID + 2 * lane + 1], acc1);
    }
    if (valid) Yb[(size_t)node * 64 + lane] = packbf2(acc0, acc1);
}

// ---------------- MFMA GEMM: Hb = dinv[row] * (gelu(BN(Yb)) @ W) -> bf16 ----------------

__global__ __launch_bounds__(256) void k_gemm128m(
        const unsigned* __restrict__ Yb, const float* __restrict__ stats,
        const float* __restrict__ g, const float* __restrict__ be,
        const unsigned* __restrict__ Wt, const float* __restrict__ dinv,
        unsigned* __restrict__ Hb) {
    __shared__ __align__(16) unsigned act[64 * 64];   // 16 KB
    __shared__ float sc_s[HID];
    __shared__ float sh_s[HID];
    int tid = threadIdx.x;
    if (tid < HID) {
        const float inv_n = 1.0f / (float)N_NODES;
        float mean = stats[tid] * inv_n;
        float var = stats[HID + tid] * inv_n - mean * mean;
        float s = g[tid] * rsqrtf(var + BN_EPS);
        sc_s[tid] = s;
        sh_s[tid] = be[tid] - mean * s;
    }
    __syncthreads();
    int row0 = blockIdx.x * 64;
    #pragma unroll
    for (int it = 0; it < 8; ++it) {
        int idx = it * 256 + tid;
        int r = idx >> 5;
        int c2 = idx & 31;
        int gr = row0 + r;
        uint2 v = make_uint2(0u, 0u);
        if (gr < N_NODES) v = *(const uint2*)(Yb + (size_t)gr * 64 + c2 * 2);
        int c = c2 * 2;
        float x0 = gelu_f(fmaf(bflo(v.x), sc_s[2 * c], sh_s[2 * c]));
        float x1 = gelu_f(fmaf(bfhi(v.x), sc_s[2 * c + 1], sh_s[2 * c + 1]));
        float x2 = gelu_f(fmaf(bflo(v.y), sc_s[2 * c + 2], sh_s[2 * c + 2]));
        float x3 = gelu_f(fmaf(bfhi(v.y), sc_s[2 * c + 3], sh_s[2 * c + 3]));
        int swz = (r & 7) << 2;
        act[r * 64 + (c ^ swz)]       = packbf2(x0, x1);
        act[r * 64 + ((c + 1) ^ swz)] = packbf2(x2, x3);
    }
    __syncthreads();
    int l = tid & 63;
    int w = tid >> 6;
    int r0 = w * 16;
    int arow = r0 + (l & 15);
    int kgrp = l >> 4;
    bf16x8 afrag[4];
    #pragma unroll
    for (int kk = 0; kk < 4; ++kk) {
        int base = (kk * 16 + kgrp * 4) ^ ((arow & 7) << 2);
        afrag[kk] = *(const bf16x8*)&act[arow * 64 + base];
    }
    float dv[4];
    #pragma unroll
    for (int reg = 0; reg < 4; ++reg) {
        int gr = row0 + r0 + kgrp * 4 + reg;
        dv[reg] = (gr < N_NODES) ? dinv[gr] : 0.0f;
    }
    unsigned short* Hb16 = (unsigned short*)Hb;
    #pragma unroll
    for (int n0 = 0; n0 < 8; ++n0) {
        f32x4 acc = {0.0f, 0.0f, 0.0f, 0.0f};
        #pragma unroll
        for (int kk = 0; kk < 4; ++kk) {
            bf16x8 b = *(const bf16x8*)&Wt[(n0 * 16 + (l & 15)) * 64 + kk * 16 + kgrp * 4];
            acc = __builtin_amdgcn_mfma_f32_16x16x32_bf16(afrag[kk], b, acc, 0, 0, 0);
        }
        int colg = n0 * 16 + (l & 15);
        #pragma unroll
        for (int reg = 0; reg < 4; ++reg) {
            int gr = row0 + r0 + kgrp * 4 + reg;
            if (gr < N_NODES)
                Hb16[(size_t)gr * HID + colg] = (unsigned short)f2bf(dv[reg] * acc[reg]);
        }
    }
}

// ---------------- conv (pre-scaled bf16 gather): padded rows, group predication ----------------

__global__ void k_convb(const unsigned* __restrict__ Hb, const int* __restrict__ rowp,
                        const int* __restrict__ rowpEnd, const int* __restrict__ col,
                        const float* __restrict__ dinv,
                        const float* __restrict__ bias, unsigned* __restrict__ Yb) {
    int tid = threadIdx.x;
    int wid = tid >> 6;
    int lane = tid & 63;
    int g = lane >> 4;
    int j = lane & 15;
    int node = blockIdx.x * 4 + wid;
    if (node >= N_NODES) return;
    int rp0 = rowp[node], rp1 = rowpEnd[node];
    float di = dinv[node];
    uint4 sv = *(const uint4*)(Hb + (size_t)node * 64 + j * 4);
    float w0 = (g == 0) ? 1.0f : 0.0f;
    float a0 = w0 * bflo(sv.x), a1 = w0 * bfhi(sv.x);
    float a2 = w0 * bflo(sv.y), a3 = w0 * bfhi(sv.y);
    float a4 = w0 * bflo(sv.z), a5 = w0 * bfhi(sv.z);
    float a6 = w0 * bflo(sv.w), a7 = w0 * bfhi(sv.w);
    if (rp0 < rp1) {
        int4 cA = *(const int4*)(col + rp0 + 4 * g);
        int4 cB = *(const int4*)(col + rp0 + 16 + 4 * g);
        for (int e0 = rp0; e0 < rp1; e0 += 32) {
            int4 nA = *(const int4*)(col + e0 + 32 + 4 * g);       // prefetch
            int4 nB = *(const int4*)(col + e0 + 48 + 4 * g);
            bool vA = (e0 + 4 * g) < rp1;
            bool vB = (e0 + 16 + 4 * g) < rp1;
            int s0 = vA ? cA.x : N_NODES;
            int s1 = vA ? cA.y : N_NODES;
            int s2 = vA ? cA.z : N_NODES;
            int s3 = vA ? cA.w : N_NODES;
            int s4 = vB ? cB.x : N_NODES;
            int s5 = vB ? cB.y : N_NODES;
            int s6 = vB ? cB.z : N_NODES;
            int s7 = vB ? cB.w : N_NODES;
            uint4 v0 = *(const uint4*)(Hb + (size_t)s0 * 64 + j * 4);
            uint4 v1 = *(const uint4*)(Hb + (size_t)s1 * 64 + j * 4);
            uint4 v2 = *(const uint4*)(Hb + (size_t)s2 * 64 + j * 4);
            uint4 v3 = *(const uint4*)(Hb + (size_t)s3 * 64 + j * 4);
            uint4 v4 = *(const uint4*)(Hb + (size_t)s4 * 64 + j * 4);
            uint4 v5 = *(const uint4*)(Hb + (size_t)s5 * 64 + j * 4);
            uint4 v6 = *(const uint4*)(Hb + (size_t)s6 * 64 + j * 4);
            uint4 v7 = *(const uint4*)(Hb + (size_t)s7 * 64 + j * 4);
            ACC8(v0); ACC8(v1); ACC8(v2); ACC8(v3);
            ACC8(v4); ACC8(v5); ACC8(v6); ACC8(v7);
            cA = nA; cB = nB;
        }
    }
    #define RED(o) { a0 += __shfl(a0,(lane+o)&63,64); a1 += __shfl(a1,(lane+o)&63,64); \
                     a2 += __shfl(a2,(lane+o)&63,64); a3 += __shfl(a3,(lane+o)&63,64); \
                     a4 += __shfl(a4,(lane+o)&63,64); a5 += __shfl(a5,(lane+o)&63,64); \
                     a6 += __shfl(a6,(lane+o)&63,64); a7 += __shfl(a7,(lane+o)&63,64); }
    RED(32); RED(16);
    #undef RED
    if (g == 0) {
        const float4* bp = (const float4*)(bias + 8 * j);
        float4 bA = bp[0], bB = bp[1];
        uint4 o;
        o.x = packbf2(fmaf(di, a0, bA.x), fmaf(di, a1, bA.y));
        o.y = packbf2(fmaf(di, a2, bA.z), fmaf(di, a3, bA.w));
        o.z = packbf2(fmaf(di, a4, bB.x), fmaf(di, a5, bB.y));
        o.w = packbf2(fmaf(di, a6, bB.z), fmaf(di, a7, bB.w));
        *(uint4*)(Yb + (size_t)node * 64 + j * 4) = o;
    }
}

// ---------------- BN stats over bf16 Y (uint4 loads, 16 lanes/row) ----------------

__global__ void k_statsb(const unsigned* __restrict__ Yb, float* __restrict__ stats) {
    __shared__ float red[16][128];
    __shared__ float red2[16][128];
    int tid = threadIdx.x;
    int j = tid & 15;
    int rg = tid >> 4;
    float s[8] = {0, 0, 0, 0, 0, 0, 0, 0};
    float q[8] = {0, 0, 0, 0, 0, 0, 0, 0};
    for (int r = blockIdx.x * 16 + rg; r < N_NODES; r += gridDim.x * 16) {
        uint4 v = *(const uint4*)(Yb + (size_t)r * 64 + j * 4);
        float x;
        x = bflo(v.x); s[0] += x; q[0] = fmaf(x, x, q[0]);
        x = bfhi(v.x); s[1] += x; q[1] = fmaf(x, x, q[1]);
        x = bflo(v.y); s[2] += x; q[2] = fmaf(x, x, q[2]);
        x = bfhi(v.y); s[3] += x; q[3] = fmaf(x, x, q[3]);
        x = bflo(v.z); s[4] += x; q[4] = fmaf(x, x, q[4]);
        x = bfhi(v.z); s[5] += x; q[5] = fmaf(x, x, q[5]);
        x = bflo(v.w); s[6] += x; q[6] = fmaf(x, x, q[6]);
        x = bfhi(v.w); s[7] += x; q[7] = fmaf(x, x, q[7]);
    }
    #pragma unroll
    for (int k = 0; k < 8; ++k) {
        red[rg][8 * j + k]  = s[k];
        red2[rg][8 * j + k] = q[k];
    }
    __syncthreads();
    if (tid < 128) {
        float S = 0.0f, Q = 0.0f;
        #pragma unroll
        for (int r = 0; r < 16; ++r) { S += red[r][tid]; Q += red2[r][tid]; }
        atomicAdd(&stats[tid], S);
        atomicAdd(&stats[128 + tid], Q);
    }
}

// ---------------- fused pool + MLP head ----------------

__device__ __forceinline__ int lowerb(const int* __restrict__ arr, int n, int key) {
    int lo = 0, hi = n;
    while (lo < hi) {
        int mid = (lo + hi) >> 1;
        if (arr[mid] < key) lo = mid + 1; else hi = mid;
    }
    return lo;
}

__global__ void k_pool_mlp(const unsigned* __restrict__ Yb, const float* __restrict__ stats,
                           const float* __restrict__ g, const float* __restrict__ be,
                           const int* __restrict__ batch,
                           const float* __restrict__ Wl1, const float* __restrict__ bl1,
                           const float* __restrict__ Wl2, const float* __restrict__ bl2,
                           float* __restrict__ out) {
    __shared__ float pooled[128];
    __shared__ float part[2][128];
    __shared__ float sc_s[128];
    __shared__ float sh_s[128];
    __shared__ int bounds[2];
    int gidx = blockIdx.x;
    int tid = threadIdx.x;
    if (tid < 128) {
        const float inv_n = 1.0f / (float)N_NODES;
        float mean = stats[tid] * inv_n;
        float var = stats[128 + tid] * inv_n - mean * mean;
        float s = g[tid] * rsqrtf(var + BN_EPS);
        sc_s[tid] = s;
        sh_s[tid] = be[tid] - mean * s;
    }
    if (tid == 0) {
        bounds[0] = lowerb(batch, N_NODES, gidx);
        bounds[1] = lowerb(batch, N_NODES, gidx + 1);
    }
    __syncthreads();
    int lo = bounds[0], hi = bounds[1];
    int rofs = tid >> 6;
    int w = tid & 63;
    float sA = sc_s[2 * w], hA = sh_s[2 * w];
    float sB = sc_s[2 * w + 1], hB = sh_s[2 * w + 1];
    float accA = 0.0f, accB = 0.0f;
    for (int r = lo + rofs; r < hi; r += 2) {
        unsigned v = Yb[(size_t)r * 64 + w];
        accA += gelu_f(fmaf(bflo(v), sA, hA));
        accB += gelu_f(fmaf(bfhi(v), sB, hB));
    }
    part[rofs][2 * w]     = accA;
    part[rofs][2 * w + 1] = accB;
    __syncthreads();
    if (tid < 128)
        pooled[tid] = (hi > lo) ? (part[0][tid] + part[1][tid]) / (float)(hi - lo) : 0.0f;
    __syncthreads();
    if (tid < 64) {
        float hs = bl1[tid];
        #pragma unroll 4
        for (int k = 0; k < 128; ++k)
            hs = fmaf(pooled[k], Wl1[k * 64 + tid], hs);
        float e = (hs > 0.0f) ? hs : expm1f(hs);
        float pv = e * Wl2[tid];
        #pragma unroll
        for (int o = 32; o > 0; o >>= 1)
            pv += __shfl_down(pv, o);
        if (tid == 0) out[gidx] = pv + bl2[0];
    }
}

// ---------------- host launch ----------------

extern "C" void kernel_launch(void* const* d_in, const int* in_sizes, int n_in,
                              void* d_out, int out_size, void* d_ws, size_t ws_size,
                              hipStream_t stream) {
    const float* x   = (const float*)d_in[0];
    const int*   ei  = (const int*)d_in[1];
    const int*   bat = (const int*)d_in[2];
    const float* W1  = (const float*)d_in[3];
    const float* b1  = (const float*)d_in[4];
    const float* g1  = (const float*)d_in[5];
    const float* be1 = (const float*)d_in[6];
    const float* W2  = (const float*)d_in[7];
    const float* b2  = (const float*)d_in[8];
    const float* g2  = (const float*)d_in[9];
    const float* be2 = (const float*)d_in[10];
    const float* W3  = (const float*)d_in[11];
    const float* b3  = (const float*)d_in[12];
    const float* g3  = (const float*)d_in[13];
    const float* be3 = (const float*)d_in[14];
    const float* Wl1 = (const float*)d_in[15];
    const float* bl1 = (const float*)d_in[16];
    const float* Wl2 = (const float*)d_in[17];
    const float* bl2 = (const float*)d_in[18];
    float* out = (float*)d_out;

    char* ws = (char*)d_ws;
    size_t off = 0;
    auto alloc = [&](size_t bytes) -> char* {
        char* p = ws + off;
        off += (bytes + 255) & ~(size_t)255;
        return p;
    };
    int*      gcnt    = (int*)alloc(NB_BUCK * sizeof(int));
    unsigned* epack   = (unsigned*)alloc(((size_t)NB_BUCK * BUCK_CAP + 64) * sizeof(unsigned));
    int*      rowp    = (int*)alloc(N_NODES * sizeof(int));
    int*      rowpEnd = (int*)alloc(N_NODES * sizeof(int));
    float*    dinv    = (float*)alloc(N_NODES * sizeof(float));
    int*      col     = (int*)alloc(((size_t)NB_BUCK * COL_CAP + 64) * sizeof(int));
    unsigned* Xb      = (unsigned*)alloc((size_t)(N_NODES + 1) * 32 * sizeof(unsigned));
    unsigned* Ybuf    = (unsigned*)alloc((size_t)N_NODES * 64 * sizeof(unsigned));
    unsigned* Hbuf    = (unsigned*)alloc((size_t)(N_NODES + 1) * 64 * sizeof(unsigned));
    float*    stats   = (float*)alloc(3 * 256 * sizeof(float));
    unsigned* Wt2     = (unsigned*)alloc(8192 * sizeof(unsigned));
    unsigned* Wt3     = (unsigned*)alloc(8192 * sizeof(unsigned));

    // ---- graph structure + casts ----
    k_init<<<65, 256, 0, stream>>>(gcnt, stats, Xb + (size_t)N_NODES * 32,
                                   Hbuf + (size_t)N_NODES * 64, W2, W3, Wt2, Wt3);
    k_bin<<<BIN_GRID, 256, 0, stream>>>(ei, gcnt, epack);
    k_fill<<<NB_BUCK, BUCK_SIZE, 0, stream>>>(gcnt, epack, rowp, rowpEnd, dinv, col, x, Xb);

    const int gemm_blocks = (N_NODES + 63) / 64;
    const int conv_blocks = (N_NODES + 3) / 4;

    // ---- layer 1 (fused aggregate + GEMM) ----
    k_conv1<<<(N_NODES + C1_NODES - 1) / C1_NODES, 512, 0, stream>>>(
        Xb, rowp, rowpEnd, col, dinv, W1, b1, Ybuf);
    k_statsb<<<1024, 256, 0, stream>>>(Ybuf, stats + 0 * 256);

    // ---- layer 2 ----
    k_gemm128m<<<gemm_blocks, 256, 0, stream>>>(Ybuf, stats + 0 * 256, g1, be1, Wt2, dinv, Hbuf);
    k_convb<<<conv_blocks, 256, 0, stream>>>(Hbuf, rowp, rowpEnd, col, dinv, b2, Ybuf);
    k_statsb<<<1024, 256, 0, stream>>>(Ybuf, stats + 1 * 256);

    // ---- layer 3 ----
    k_gemm128m<<<gemm_blocks, 256, 0, stream>>>(Ybuf, stats + 1 * 256, g2, be2, Wt3, dinv, Hbuf);
    k_convb<<<conv_blocks, 256, 0, stream>>>(Hbuf, rowp, rowpEnd, col, dinv, b3, Ybuf);
    k_statsb<<<1024, 256, 0, stream>>>(Ybuf, stats + 2 * 256);

    // ---- pool + head ----
    k_pool_mlp<<<NUM_GRAPHS, 128, 0, stream>>>(Ybuf, stats + 2 * 256, g3, be3, bat,
                                               Wl1, bl1, Wl2, bl2, out);
}

// Round 12
// 635.228 us; speedup vs baseline: 1.0989x; 1.0989x over previous
//
#include <hip/hip_runtime.h>
#include <hip/hip_bf16.h>
#include <math.h>

#define N_NODES 100000
#define N_EDGES 3200000
#define NUM_GRAPHS 2048
#define IN_CH 35
#define HID 128
#define BN_EPS 1e-5f

#define BUCK_SHIFT 9
#define BUCK_SIZE 512
#define NB_BUCK 196          // ceil(100000/512)
#define BUCK_CAP 18432       // capacity/bucket (mean 16327 + ~16 sigma)
#define BIN_GRID 1024
#define BIN_CHUNK 3128       // multiple of 4; 1024*3128 >= 3.2M
#define NSLOT 128            // stat partial slots

typedef short bf16x8 __attribute__((ext_vector_type(8)));
typedef float f32x4 __attribute__((ext_vector_type(4)));

__device__ __forceinline__ float gelu_f(float x) {
    return 0.5f * x * (1.0f + erff(x * 0.70710678118654752440f));
}

__device__ __forceinline__ float bflo(unsigned v) { return __uint_as_float(v << 16); }
__device__ __forceinline__ float bfhi(unsigned v) { return __uint_as_float(v & 0xffff0000u); }
__device__ __forceinline__ unsigned f2bf(float f) {
    unsigned x = __float_as_uint(f);
    return (x + 0x7fffu + ((x >> 16) & 1u)) >> 16;   // RNE
}
__device__ __forceinline__ unsigned packbf2(float lo, float hi) {
    return f2bf(lo) | (f2bf(hi) << 16);
}

// ---------------- init: W2/W3 transpose-cast + zero partials/counters/pad rows ----------------

__global__ void k_init(int* __restrict__ gcnt, float* __restrict__ pstat,
                       unsigned* __restrict__ xzero, unsigned* __restrict__ hzero,
                       const float* __restrict__ W2, const float* __restrict__ W3,
                       unsigned* __restrict__ Wt2, unsigned* __restrict__ Wt3) {
    int b = blockIdx.x;
    if (b < 64) {
        int t = b * 256 + threadIdx.x;   // 0..16383
        const float* W = (t < 8192) ? W2 : W3;
        unsigned* Wt = (t < 8192) ? Wt2 : Wt3;
        int i = t & 8191;
        int n = i >> 6, j = i & 63;
        Wt[n * 64 + j] = packbf2(W[(2 * j) * HID + n], W[(2 * j + 1) * HID + n]);
    } else if (b < 64 + 3 * NSLOT) {
        pstat[(size_t)(b - 64) * 256 + threadIdx.x] = 0.0f;
    } else {
        int i = threadIdx.x;
        if (i < NB_BUCK) gcnt[i] = 0;
        if (i < 32) xzero[i] = 0u;   // Xb pad row (node N_NODES)
        if (i < 64) hzero[i] = 0u;   // Hb pad row (node N_NODES)
    }
}

// ---------------- bin: one pass, fixed-capacity buckets, packed edges ----------------
// edge word: src (bits 0..16) | (dst & 511) (bits 17..25)

__global__ void k_bin(const int* __restrict__ ei, int* __restrict__ gcnt,
                      unsigned* __restrict__ epack) {
    __shared__ unsigned lpack[BIN_CHUNK];
    __shared__ unsigned char lbuck[BIN_CHUNK];
    __shared__ int hist[NB_BUCK];
    __shared__ int hbase[NB_BUCK];
    __shared__ int lcur[NB_BUCK];
    int tid = threadIdx.x;
    if (tid < NB_BUCK) { hist[tid] = 0; lcur[tid] = 0; }
    __syncthreads();
    int e0 = blockIdx.x * BIN_CHUNK;
    int nE = min(e0 + BIN_CHUNK, N_EDGES) - e0;   // multiple of 4
    for (int i = tid * 4; i < nE; i += 1024) {
        int4 s4 = *(const int4*)(ei + e0 + i);
        int4 d4 = *(const int4*)(ei + N_EDGES + e0 + i);
        lpack[i + 0] = (unsigned)s4.x | (((unsigned)d4.x & 511u) << 17);
        lpack[i + 1] = (unsigned)s4.y | (((unsigned)d4.y & 511u) << 17);
        lpack[i + 2] = (unsigned)s4.z | (((unsigned)d4.z & 511u) << 17);
        lpack[i + 3] = (unsigned)s4.w | (((unsigned)d4.w & 511u) << 17);
        int b0 = d4.x >> BUCK_SHIFT, b1 = d4.y >> BUCK_SHIFT;
        int b2 = d4.z >> BUCK_SHIFT, b3 = d4.w >> BUCK_SHIFT;
        lbuck[i + 0] = (unsigned char)b0;
        lbuck[i + 1] = (unsigned char)b1;
        lbuck[i + 2] = (unsigned char)b2;
        lbuck[i + 3] = (unsigned char)b3;
        atomicAdd(&hist[b0], 1);
        atomicAdd(&hist[b1], 1);
        atomicAdd(&hist[b2], 1);
        atomicAdd(&hist[b3], 1);
    }
    __syncthreads();
    if (tid < NB_BUCK) {
        int h = hist[tid];
        hbase[tid] = (h > 0) ? (tid * BUCK_CAP + atomicAdd(&gcnt[tid], h)) : 0;
    }
    __syncthreads();
    for (int i = tid; i < nE; i += 256) {
        int b = lbuck[i];
        int off = atomicAdd(&lcur[b], 1);
        epack[hbase[b] + off] = lpack[i];
    }
}

// ---------------- fill: per-bucket degree, rowp/rowpEnd, dinv, CSR col ----------------

__global__ void k_fill(const int* __restrict__ gcnt, const unsigned* __restrict__ epack,
                       int* __restrict__ rowp, int* __restrict__ rowpEnd,
                       float* __restrict__ dinv, int* __restrict__ col) {
    __shared__ int ldeg[BUCK_SIZE];
    __shared__ int sa[BUCK_SIZE];
    __shared__ int sb[BUCK_SIZE];
    __shared__ int lcur[BUCK_SIZE];
    int b = blockIdx.x;
    int tid = threadIdx.x;
    int base_node = b << BUCK_SHIFT;
    int nn = min(BUCK_SIZE, N_NODES - base_node);
    int seg0 = b * BUCK_CAP;
    int seg1 = seg0 + gcnt[b];
    ldeg[tid] = 0;
    __syncthreads();
    for (int e = seg0 + tid; e < seg1; e += BUCK_SIZE)
        atomicAdd(&ldeg[epack[e] >> 17], 1);
    __syncthreads();
    sa[tid] = ldeg[tid];
    __syncthreads();
    int* src = sa; int* dst = sb;
    for (int st = 1; st < BUCK_SIZE; st <<= 1) {
        int v = src[tid];
        if (tid >= st) v += src[tid - st];
        dst[tid] = v;
        __syncthreads();
        int* t = src; src = dst; dst = t;
    }
    int ex = (tid == 0) ? 0 : src[tid - 1];
    int rp = seg0 + ex;
    lcur[tid] = rp;
    if (tid < nn) {
        rowp[base_node + tid] = rp;
        rowpEnd[base_node + tid] = rp + ldeg[tid];
        dinv[base_node + tid] = rsqrtf((float)(ldeg[tid] + 1));
    }
    __syncthreads();
    for (int e = seg0 + tid; e < seg1; e += BUCK_SIZE) {
        unsigned v = epack[e];
        int p = atomicAdd(&lcur[v >> 17], 1);
        col[p] = (int)(v & 0x1FFFFu);
    }
}

// ---------------- cast X -> pre-scaled bf16 rows: Xb[n] = dinv[n]*X[n] ----------------

__global__ void k_castx(const float* __restrict__ X, const float* __restrict__ dinv,
                        unsigned* __restrict__ Xb) {
    int i = blockIdx.x * blockDim.x + threadIdx.x;
    if (i >= N_NODES * 32) return;
    int n = i >> 5, j = i & 31;
    float dv = dinv[n];
    float lo = 0.0f, hi = 0.0f;
    if (j < 17) {
        lo = X[(size_t)n * IN_CH + 2 * j];
        hi = X[(size_t)n * IN_CH + 2 * j + 1];
    } else if (j == 17) {
        lo = X[(size_t)n * IN_CH + 34];
    }
    Xb[i] = packbf2(dv * lo, dv * hi);
}

#define ACC8(v) { a0 += bflo(v.x); a1 += bfhi(v.x); a2 += bflo(v.y); a3 += bfhi(v.y); \
                  a4 += bflo(v.z); a5 += bfhi(v.z); a6 += bflo(v.w); a7 += bfhi(v.w); }
#define ACC4(v) { a0 += bflo(v.x); a1 += bfhi(v.x); a2 += bflo(v.y); a3 += bfhi(v.y); }

// ---------------- fused layer-1: Y1 = (A_norm X) W1 + b1 -> bf16 (+stat partials) ----------------
// 32 edges in flight per wave: 4 groups x 16 lanes, group g owns 4-edge runs at
// e0+4g and e0+16+4g (2 int4 index loads, 8 uint2 row loads per iteration).

#define C1_NODES 8

__global__ __launch_bounds__(512) void k_conv1(
        const unsigned* __restrict__ Xb, const int* __restrict__ rowp,
        const int* __restrict__ rowpEnd, const int* __restrict__ col,
        const float* __restrict__ dinv,
        const float* __restrict__ W1, const float* __restrict__ b1,
        unsigned* __restrict__ Yb, float* __restrict__ pstat) {
    __shared__ float w_s[IN_CH * HID];       // 17.9 KB
    __shared__ float b_s[HID];
    __shared__ float xa_s[C1_NODES][36];
    __shared__ float lsum[C1_NODES][256];    // 8 KB: per-wave sum[128]+sumsq[128]
    int tid = threadIdx.x;
    for (int u = tid; u < IN_CH * HID; u += 512) w_s[u] = W1[u];
    if (tid < HID) b_s[tid] = b1[tid];

    int wid = tid >> 6;
    int lane = tid & 63;
    int g = lane >> 4;
    int j = lane & 15;
    int node = blockIdx.x * C1_NODES + wid;
    bool valid = node < N_NODES;

    float a0 = 0.0f, a1 = 0.0f, a2 = 0.0f, a3 = 0.0f;
    float di = 0.0f;
    if (valid) {
        int rp0 = rowp[node], rp1 = rowpEnd[node];
        di = dinv[node];
        uint2 sv = *(const uint2*)(Xb + (size_t)node * 32 + j * 2);
        float w0 = (g == 0) ? 1.0f : 0.0f;
        a0 = w0 * bflo(sv.x); a1 = w0 * bfhi(sv.x);
        a2 = w0 * bflo(sv.y); a3 = w0 * bfhi(sv.y);
        unsigned deg = (unsigned)(rp1 - rp0);
        for (int e0 = (rp0 & ~3); e0 < rp1; e0 += 32) {
            int ebA = e0 + 4 * g;
            int ebB = ebA + 16;
            int4 cA = *(const int4*)(col + ebA);
            int4 cB = *(const int4*)(col + ebB);
            int s0 = ((unsigned)(ebA + 0 - rp0) < deg) ? cA.x : N_NODES;
            int s1 = ((unsigned)(ebA + 1 - rp0) < deg) ? cA.y : N_NODES;
            int s2 = ((unsigned)(ebA + 2 - rp0) < deg) ? cA.z : N_NODES;
            int s3 = ((unsigned)(ebA + 3 - rp0) < deg) ? cA.w : N_NODES;
            int s4 = ((unsigned)(ebB + 0 - rp0) < deg) ? cB.x : N_NODES;
            int s5 = ((unsigned)(ebB + 1 - rp0) < deg) ? cB.y : N_NODES;
            int s6 = ((unsigned)(ebB + 2 - rp0) < deg) ? cB.z : N_NODES;
            int s7 = ((unsigned)(ebB + 3 - rp0) < deg) ? cB.w : N_NODES;
            uint2 v0 = *(const uint2*)(Xb + (size_t)s0 * 32 + j * 2);
            uint2 v1 = *(const uint2*)(Xb + (size_t)s1 * 32 + j * 2);
            uint2 v2 = *(const uint2*)(Xb + (size_t)s2 * 32 + j * 2);
            uint2 v3 = *(const uint2*)(Xb + (size_t)s3 * 32 + j * 2);
            uint2 v4 = *(const uint2*)(Xb + (size_t)s4 * 32 + j * 2);
            uint2 v5 = *(const uint2*)(Xb + (size_t)s5 * 32 + j * 2);
            uint2 v6 = *(const uint2*)(Xb + (size_t)s6 * 32 + j * 2);
            uint2 v7 = *(const uint2*)(Xb + (size_t)s7 * 32 + j * 2);
            ACC4(v0); ACC4(v1); ACC4(v2); ACC4(v3);
            ACC4(v4); ACC4(v5); ACC4(v6); ACC4(v7);
        }
    }
    a0 += __shfl(a0, (lane + 32) & 63, 64);
    a1 += __shfl(a1, (lane + 32) & 63, 64);
    a2 += __shfl(a2, (lane + 32) & 63, 64);
    a3 += __shfl(a3, (lane + 32) & 63, 64);
    a0 += __shfl(a0, (lane + 16) & 63, 64);
    a1 += __shfl(a1, (lane + 16) & 63, 64);
    a2 += __shfl(a2, (lane + 16) & 63, 64);
    a3 += __shfl(a3, (lane + 16) & 63, 64);
    if (valid && g == 0 && j < 9) {
        xa_s[wid][4 * j + 0] = di * a0;
        xa_s[wid][4 * j + 1] = di * a1;
        xa_s[wid][4 * j + 2] = di * a2;
        xa_s[wid][4 * j + 3] = di * a3;
    }
    __syncthreads();
    float acc0 = b_s[2 * lane];
    float acc1 = b_s[2 * lane + 1];
    #pragma unroll 7
    for (int k = 0; k < IN_CH; ++k) {
        float xv = xa_s[wid][k];
        acc0 = fmaf(xv, w_s[k * HID + 2 * lane], acc0);
        acc1 = fmaf(xv, w_s[k * HID + 2 * lane + 1], acc1);
    }
    if (valid) Yb[(size_t)node * 64 + lane] = packbf2(acc0, acc1);
    // ---- stat partials: per-wave slab then one global add per channel ----
    lsum[wid][2 * lane]           = acc0;
    lsum[wid][2 * lane + 1]       = acc1;
    lsum[wid][128 + 2 * lane]     = acc0 * acc0;
    lsum[wid][128 + 2 * lane + 1] = acc1 * acc1;
    __syncthreads();
    if (tid < 256) {
        float v = 0.0f;
        #pragma unroll
        for (int wv = 0; wv < C1_NODES; ++wv) v += lsum[wv][tid];
        atomicAdd(&pstat[(size_t)(blockIdx.x & (NSLOT - 1)) * 256 + tid], v);
    }
}

// ---------------- stat finalize: partials -> scale/shift ----------------

__global__ void k_statfin(const float* __restrict__ pstat, const float* __restrict__ g,
                          const float* __restrict__ be, float* __restrict__ scsh) {
    __shared__ float red[4][256];
    int tid = threadIdx.x;           // 1024
    int c = tid & 255;
    int grp = tid >> 8;              // 0..3
    float S = 0.0f;
    for (int s = grp; s < NSLOT; s += 4) S += pstat[(size_t)s * 256 + c];
    red[grp][c] = S;
    __syncthreads();
    if (tid < 128) {
        float Ssum = red[0][tid] + red[1][tid] + red[2][tid] + red[3][tid];
        float Qsum = red[0][128 + tid] + red[1][128 + tid] + red[2][128 + tid] + red[3][128 + tid];
        const float inv_n = 1.0f / (float)N_NODES;
        float mean = Ssum * inv_n;
        float var = Qsum * inv_n - mean * mean;
        float sc = g[tid] * rsqrtf(var + BN_EPS);
        scsh[tid] = sc;
        scsh[128 + tid] = be[tid] - mean * sc;
    }
}

// ---------------- MFMA GEMM: Hb = dinv[row] * (gelu(BN(Yb)) @ W) -> bf16 ----------------

__global__ __launch_bounds__(256) void k_gemm128m(
        const unsigned* __restrict__ Yb, const float* __restrict__ scsh,
        const unsigned* __restrict__ Wt, const float* __restrict__ dinv,
        unsigned* __restrict__ Hb) {
    __shared__ __align__(16) unsigned act[64 * 64];   // 16 KB
    __shared__ float sc_s[HID];
    __shared__ float sh_s[HID];
    int tid = threadIdx.x;
    if (tid < HID) {
        sc_s[tid] = scsh[tid];
        sh_s[tid] = scsh[128 + tid];
    }
    __syncthreads();
    int row0 = blockIdx.x * 64;
    #pragma unroll
    for (int it = 0; it < 8; ++it) {
        int idx = it * 256 + tid;
        int r = idx >> 5;
        int c2 = idx & 31;
        int gr = row0 + r;
        uint2 v = make_uint2(0u, 0u);
        if (gr < N_NODES) v = *(const uint2*)(Yb + (size_t)gr * 64 + c2 * 2);
        int c = c2 * 2;
        float x0 = gelu_f(fmaf(bflo(v.x), sc_s[2 * c], sh_s[2 * c]));
        float x1 = gelu_f(fmaf(bfhi(v.x), sc_s[2 * c + 1], sh_s[2 * c + 1]));
        float x2 = gelu_f(fmaf(bflo(v.y), sc_s[2 * c + 2], sh_s[2 * c + 2]));
        float x3 = gelu_f(fmaf(bfhi(v.y), sc_s[2 * c + 3], sh_s[2 * c + 3]));
        int swz = (r & 7) << 2;
        act[r * 64 + (c ^ swz)]       = packbf2(x0, x1);
        act[r * 64 + ((c + 1) ^ swz)] = packbf2(x2, x3);
    }
    __syncthreads();
    int l = tid & 63;
    int w = tid >> 6;
    int r0 = w * 16;
    int arow = r0 + (l & 15);
    int kgrp = l >> 4;
    bf16x8 afrag[4];
    #pragma unroll
    for (int kk = 0; kk < 4; ++kk) {
        int base = (kk * 16 + kgrp * 4) ^ ((arow & 7) << 2);
        afrag[kk] = *(const bf16x8*)&act[arow * 64 + base];
    }
    float dv[4];
    #pragma unroll
    for (int reg = 0; reg < 4; ++reg) {
        int gr = row0 + r0 + kgrp * 4 + reg;
        dv[reg] = (gr < N_NODES) ? dinv[gr] : 0.0f;
    }
    unsigned short* Hb16 = (unsigned short*)Hb;
    #pragma unroll
    for (int n0 = 0; n0 < 8; ++n0) {
        f32x4 acc = {0.0f, 0.0f, 0.0f, 0.0f};
        #pragma unroll
        for (int kk = 0; kk < 4; ++kk) {
            bf16x8 b = *(const bf16x8*)&Wt[(n0 * 16 + (l & 15)) * 64 + kk * 16 + kgrp * 4];
            acc = __builtin_amdgcn_mfma_f32_16x16x32_bf16(afrag[kk], b, acc, 0, 0, 0);
        }
        int colg = n0 * 16 + (l & 15);
        #pragma unroll
        for (int reg = 0; reg < 4; ++reg) {
            int gr = row0 + r0 + kgrp * 4 + reg;
            if (gr < N_NODES)
                Hb16[(size_t)gr * HID + colg] = (unsigned short)f2bf(dv[reg] * acc[reg]);
        }
    }
}

// ---------------- conv (pre-scaled bf16 gather) + stat partials ----------------
// 4 waves = 4 nodes/block (exact: 25000*4 = 100000); 4 groups x 16 lanes;
// uint4 row loads; 32 edges in flight.

__global__ void k_convb(const unsigned* __restrict__ Hb, const int* __restrict__ rowp,
                        const int* __restrict__ rowpEnd, const int* __restrict__ col,
                        const float* __restrict__ dinv,
                        const float* __restrict__ bias, unsigned* __restrict__ Yb,
                        float* __restrict__ pstat) {
    __shared__ float lsum[4][256];
    int tid = threadIdx.x;
    int wid = tid >> 6;
    int lane = tid & 63;
    int g = lane >> 4;
    int j = lane & 15;
    int node = blockIdx.x * 4 + wid;
    if (tid < 256) { lsum[tid >> 6][(tid & 63) * 4 + 0] = 0.0f; }   // placeholder init below
    // full zero of lsum (1024 floats) by 256 threads:
    #pragma unroll
    for (int z = 0; z < 4; ++z) ((float*)lsum)[z * 256 + tid] = 0.0f;
    __syncthreads();
    int rp0 = rowp[node], rp1 = rowpEnd[node];
    float di = dinv[node];
    uint4 sv = *(const uint4*)(Hb + (size_t)node * 64 + j * 4);
    float w0 = (g == 0) ? 1.0f : 0.0f;
    float a0 = w0 * bflo(sv.x), a1 = w0 * bfhi(sv.x);
    float a2 = w0 * bflo(sv.y), a3 = w0 * bfhi(sv.y);
    float a4 = w0 * bflo(sv.z), a5 = w0 * bfhi(sv.z);
    float a6 = w0 * bflo(sv.w), a7 = w0 * bfhi(sv.w);
    unsigned deg = (unsigned)(rp1 - rp0);
    for (int e0 = (rp0 & ~3); e0 < rp1; e0 += 32) {
        int ebA = e0 + 4 * g;
        int ebB = ebA + 16;
        int4 cA = *(const int4*)(col + ebA);
        int4 cB = *(const int4*)(col + ebB);
        int s0 = ((unsigned)(ebA + 0 - rp0) < deg) ? cA.x : N_NODES;
        int s1 = ((unsigned)(ebA + 1 - rp0) < deg) ? cA.y : N_NODES;
        int s2 = ((unsigned)(ebA + 2 - rp0) < deg) ? cA.z : N_NODES;
        int s3 = ((unsigned)(ebA + 3 - rp0) < deg) ? cA.w : N_NODES;
        int s4 = ((unsigned)(ebB + 0 - rp0) < deg) ? cB.x : N_NODES;
        int s5 = ((unsigned)(ebB + 1 - rp0) < deg) ? cB.y : N_NODES;
        int s6 = ((unsigned)(ebB + 2 - rp0) < deg) ? cB.z : N_NODES;
        int s7 = ((unsigned)(ebB + 3 - rp0) < deg) ? cB.w : N_NODES;
        uint4 v0 = *(const uint4*)(Hb + (size_t)s0 * 64 + j * 4);
        uint4 v1 = *(const uint4*)(Hb + (size_t)s1 * 64 + j * 4);
        uint4 v2 = *(const uint4*)(Hb + (size_t)s2 * 64 + j * 4);
        uint4 v3 = *(const uint4*)(Hb + (size_t)s3 * 64 + j * 4);
        uint4 v4 = *(const uint4*)(Hb + (size_t)s4 * 64 + j * 4);
        uint4 v5 = *(const uint4*)(Hb + (size_t)s5 * 64 + j * 4);
        uint4 v6 = *(const uint4*)(Hb + (size_t)s6 * 64 + j * 4);
        uint4 v7 = *(const uint4*)(Hb + (size_t)s7 * 64 + j * 4);
        ACC8(v0); ACC8(v1); ACC8(v2); ACC8(v3);
        ACC8(v4); ACC8(v5); ACC8(v6); ACC8(v7);
    }
    #define RED(o) { a0 += __shfl(a0,(lane+o)&63,64); a1 += __shfl(a1,(lane+o)&63,64); \
                     a2 += __shfl(a2,(lane+o)&63,64); a3 += __shfl(a3,(lane+o)&63,64); \
                     a4 += __shfl(a4,(lane+o)&63,64); a5 += __shfl(a5,(lane+o)&63,64); \
                     a6 += __shfl(a6,(lane+o)&63,64); a7 += __shfl(a7,(lane+o)&63,64); }
    RED(32); RED(16);
    #undef RED
    if (g == 0) {
        const float4* bp = (const float4*)(bias + 8 * j);
        float4 bA = bp[0], bB = bp[1];
        float y0 = fmaf(di, a0, bA.x), y1 = fmaf(di, a1, bA.y);
        float y2 = fmaf(di, a2, bA.z), y3 = fmaf(di, a3, bA.w);
        float y4 = fmaf(di, a4, bB.x), y5 = fmaf(di, a5, bB.y);
        float y6 = fmaf(di, a6, bB.z), y7 = fmaf(di, a7, bB.w);
        uint4 o;
        o.x = packbf2(y0, y1);
        o.y = packbf2(y2, y3);
        o.z = packbf2(y4, y5);
        o.w = packbf2(y6, y7);
        *(uint4*)(Yb + (size_t)node * 64 + j * 4) = o;
        lsum[wid][8 * j + 0] = y0; lsum[wid][8 * j + 1] = y1;
        lsum[wid][8 * j + 2] = y2; lsum[wid][8 * j + 3] = y3;
        lsum[wid][8 * j + 4] = y4; lsum[wid][8 * j + 5] = y5;
        lsum[wid][8 * j + 6] = y6; lsum[wid][8 * j + 7] = y7;
        lsum[wid][128 + 8 * j + 0] = y0 * y0; lsum[wid][128 + 8 * j + 1] = y1 * y1;
        lsum[wid][128 + 8 * j + 2] = y2 * y2; lsum[wid][128 + 8 * j + 3] = y3 * y3;
        lsum[wid][128 + 8 * j + 4] = y4 * y4; lsum[wid][128 + 8 * j + 5] = y5 * y5;
        lsum[wid][128 + 8 * j + 6] = y6 * y6; lsum[wid][128 + 8 * j + 7] = y7 * y7;
    }
    __syncthreads();
    if (tid < 256) {
        float v = lsum[0][tid] + lsum[1][tid] + lsum[2][tid] + lsum[3][tid];
        atomicAdd(&pstat[(size_t)(blockIdx.x & (NSLOT - 1)) * 256 + tid], v);
    }
}

// ---------------- fused pool + MLP head ----------------

__device__ __forceinline__ int lowerb(const int* __restrict__ arr, int n, int key) {
    int lo = 0, hi = n;
    while (lo < hi) {
        int mid = (lo + hi) >> 1;
        if (arr[mid] < key) lo = mid + 1; else hi = mid;
    }
    return lo;
}

__global__ void k_pool_mlp(const unsigned* __restrict__ Yb, const float* __restrict__ scsh,
                           const int* __restrict__ batch,
                           const float* __restrict__ Wl1, const float* __restrict__ bl1,
                           const float* __restrict__ Wl2, const float* __restrict__ bl2,
                           float* __restrict__ out) {
    __shared__ float pooled[128];
    __shared__ float part[2][128];
    __shared__ float sc_s[128];
    __shared__ float sh_s[128];
    __shared__ int bounds[2];
    int gidx = blockIdx.x;
    int tid = threadIdx.x;
    if (tid < 128) {
        sc_s[tid] = scsh[tid];
        sh_s[tid] = scsh[128 + tid];
    }
    if (tid == 0) {
        bounds[0] = lowerb(batch, N_NODES, gidx);
        bounds[1] = lowerb(batch, N_NODES, gidx + 1);
    }
    __syncthreads();
    int lo = bounds[0], hi = bounds[1];
    int rofs = tid >> 6;
    int w = tid & 63;
    float sA = sc_s[2 * w], hA = sh_s[2 * w];
    float sB = sc_s[2 * w + 1], hB = sh_s[2 * w + 1];
    float accA = 0.0f, accB = 0.0f;
    for (int r = lo + rofs; r < hi; r += 2) {
        unsigned v = Yb[(size_t)r * 64 + w];
        accA += gelu_f(fmaf(bflo(v), sA, hA));
        accB += gelu_f(fmaf(bfhi(v), sB, hB));
    }
    part[rofs][2 * w]     = accA;
    part[rofs][2 * w + 1] = accB;
    __syncthreads();
    if (tid < 128)
        pooled[tid] = (hi > lo) ? (part[0][tid] + part[1][tid]) / (float)(hi - lo) : 0.0f;
    __syncthreads();
    if (tid < 64) {
        float hs = bl1[tid];
        #pragma unroll 4
        for (int k = 0; k < 128; ++k)
            hs = fmaf(pooled[k], Wl1[k * 64 + tid], hs);
        float e = (hs > 0.0f) ? hs : expm1f(hs);
        float pv = e * Wl2[tid];
        #pragma unroll
        for (int o = 32; o > 0; o >>= 1)
            pv += __shfl_down(pv, o);
        if (tid == 0) out[gidx] = pv + bl2[0];
    }
}

// ---------------- host launch ----------------

extern "C" void kernel_launch(void* const* d_in, const int* in_sizes, int n_in,
                              void* d_out, int out_size, void* d_ws, size_t ws_size,
                              hipStream_t stream) {
    const float* x   = (const float*)d_in[0];
    const int*   ei  = (const int*)d_in[1];
    const int*   bat = (const int*)d_in[2];
    const float* W1  = (const float*)d_in[3];
    const float* b1  = (const float*)d_in[4];
    const float* g1  = (const float*)d_in[5];
    const float* be1 = (const float*)d_in[6];
    const float* W2  = (const float*)d_in[7];
    const float* b2  = (const float*)d_in[8];
    const float* g2  = (const float*)d_in[9];
    const float* be2 = (const float*)d_in[10];
    const float* W3  = (const float*)d_in[11];
    const float* b3  = (const float*)d_in[12];
    const float* g3  = (const float*)d_in[13];
    const float* be3 = (const float*)d_in[14];
    const float* Wl1 = (const float*)d_in[15];
    const float* bl1 = (const float*)d_in[16];
    const float* Wl2 = (const float*)d_in[17];
    const float* bl2 = (const float*)d_in[18];
    float* out = (float*)d_out;

    char* ws = (char*)d_ws;
    size_t off = 0;
    auto alloc = [&](size_t bytes) -> char* {
        char* p = ws + off;
        off += (bytes + 255) & ~(size_t)255;
        return p;
    };
    int*      gcnt    = (int*)alloc(NB_BUCK * sizeof(int));
    unsigned* epack   = (unsigned*)alloc(((size_t)NB_BUCK * BUCK_CAP + 64) * sizeof(unsigned));
    int*      rowp    = (int*)alloc(N_NODES * sizeof(int));
    int*      rowpEnd = (int*)alloc(N_NODES * sizeof(int));
    float*    dinv    = (float*)alloc(N_NODES * sizeof(float));
    int*      col     = (int*)alloc(((size_t)NB_BUCK * BUCK_CAP + 64) * sizeof(int));
    unsigned* Xb      = (unsigned*)alloc((size_t)(N_NODES + 1) * 32 * sizeof(unsigned));
    unsigned* Ybuf    = (unsigned*)alloc((size_t)N_NODES * 64 * sizeof(unsigned));
    unsigned* Hbuf    = (unsigned*)alloc((size_t)(N_NODES + 1) * 64 * sizeof(unsigned));
    float*    pstat   = (float*)alloc((size_t)3 * NSLOT * 256 * sizeof(float));
    float*    scsh    = (float*)alloc(3 * 256 * sizeof(float));
    unsigned* Wt2     = (unsigned*)alloc(8192 * sizeof(unsigned));
    unsigned* Wt3     = (unsigned*)alloc(8192 * sizeof(unsigned));

    // ---- graph structure + casts ----
    k_init<<<64 + 3 * NSLOT + 1, 256, 0, stream>>>(gcnt, pstat, Xb + (size_t)N_NODES * 32,
                                                   Hbuf + (size_t)N_NODES * 64, W2, W3, Wt2, Wt3);
    k_bin<<<BIN_GRID, 256, 0, stream>>>(ei, gcnt, epack);
    k_fill<<<NB_BUCK, BUCK_SIZE, 0, stream>>>(gcnt, epack, rowp, rowpEnd, dinv, col);
    k_castx<<<(N_NODES * 32 + 255) / 256, 256, 0, stream>>>(x, dinv, Xb);

    const int gemm_blocks = (N_NODES + 63) / 64;
    const int conv_blocks = N_NODES / 4;   // exact: 25000

    // ---- layer 1 (fused aggregate + GEMM + stats) ----
    k_conv1<<<N_NODES / C1_NODES, 512, 0, stream>>>(
        Xb, rowp, rowpEnd, col, dinv, W1, b1, Ybuf, pstat + 0 * NSLOT * 256);
    k_statfin<<<1, 1024, 0, stream>>>(pstat + 0 * NSLOT * 256, g1, be1, scsh + 0 * 256);

    // ---- layer 2 ----
    k_gemm128m<<<gemm_blocks, 256, 0, stream>>>(Ybuf, scsh + 0 * 256, Wt2, dinv, Hbuf);
    k_convb<<<conv_blocks, 256, 0, stream>>>(Hbuf, rowp, rowpEnd, col, dinv, b2, Ybuf,
                                             pstat + 1 * NSLOT * 256);
    k_statfin<<<1, 1024, 0, stream>>>(pstat + 1 * NSLOT * 256, g2, be2, scsh + 1 * 256);

    // ---- layer 3 ----
    k_gemm128m<<<gemm_blocks, 256, 0, stream>>>(Ybuf, scsh + 1 * 256, Wt3, dinv, Hbuf);
    k_convb<<<conv_blocks, 256, 0, stream>>>(Hbuf, rowp, rowpEnd, col, dinv, b3, Ybuf,
                                             pstat + 2 * NSLOT * 256);
    k_statfin<<<1, 1024, 0, stream>>>(pstat + 2 * NSLOT * 256, g3, be3, scsh + 2 * 256);

    // ---- pool + head ----
    k_pool_mlp<<<NUM_GRAPHS, 128, 0, stream>>>(Ybuf, scsh + 2 * 256, bat,
                                               Wl1, bl1, Wl2, bl2, out);
}